// Round 10
// baseline (203.599 us; speedup 1.0000x reference)
//
#include <hip/hip_runtime.h>
#include <hip/hip_bf16.h>

#define NB 2
#define TT 3136
#define DIM 768
#define NH 12
#define NF 16
#define NP 196

typedef __attribute__((ext_vector_type(8))) short short8;
typedef __attribute__((ext_vector_type(4))) short s16x4;
typedef __attribute__((ext_vector_type(4))) float f32x4;
typedef unsigned int uint;

__device__ __forceinline__ float bf2f(short s) {
    return __uint_as_float(((uint)(unsigned short)s) << 16);
}
__device__ __forceinline__ short f2bs(float f) {
    __hip_bfloat16 h = __float2bfloat16(f);
    short s; __builtin_memcpy(&s, &h, 2); return s;
}
__device__ __forceinline__ uint pack2bf(float a, float b) {
    return (uint)(unsigned short)f2bs(a) | ((uint)(unsigned short)f2bs(b) << 16);
}
__device__ __forceinline__ void load16_lds(const void* g, void* l) {
    __builtin_amdgcn_global_load_lds(
        (const __attribute__((address_space(1))) unsigned int*)g,
        (__attribute__((address_space(3))) unsigned int*)l, 16, 0, 0);
}

// -------- prep_all: Wq|Wkv|Wo transpose+bf16, ctx->bf16, LayerNorm(x) ------
__global__ __launch_bounds__(256)
void prep_all(const float* __restrict__ Wq, const float* __restrict__ Wkv,
              const float* __restrict__ Wo,
              __hip_bfloat16* __restrict__ WqT, __hip_bfloat16* __restrict__ WkvT,
              __hip_bfloat16* __restrict__ WoT,
              const float* __restrict__ ctx, __hip_bfloat16* __restrict__ cb,
              const float* __restrict__ x, const float* __restrict__ gamma,
              const float* __restrict__ beta, __hip_bfloat16* __restrict__ xn) {
    __shared__ float tile[32][33];
    int blk = blockIdx.x, tid = threadIdx.x;
    if (blk < 2304) {
        int bx = blk % 96, ky = blk / 96;
        const float* W; __hip_bfloat16* WT; int N, n0;
        if (bx < 24)      { W = Wq;  WT = WqT;  N = DIM;     n0 = bx * 32; }
        else if (bx < 72) { W = Wkv; WT = WkvT; N = 2 * DIM; n0 = (bx - 24) * 32; }
        else              { W = Wo;  WT = WoT;  N = DIM;     n0 = (bx - 72) * 32; }
        int k0 = ky * 32;
        int tx = tid & 31, ty = tid >> 5;
#pragma unroll
        for (int i = 0; i < 32; i += 8)
            tile[ty + i][tx] = W[(size_t)(k0 + ty + i) * N + (n0 + tx)];
        __syncthreads();
#pragma unroll
        for (int i = 0; i < 32; i += 8)
            WT[(size_t)(n0 + ty + i) * DIM + (k0 + tx)] = __float2bfloat16(tile[tx][ty + i]);
        return;
    }
    blk -= 2304;
    if (blk < 4704) {
        size_t i = (size_t)blk * 256 + tid;
        f32x4 f; __builtin_memcpy(&f, ctx + i * 4, 16);
        s16x4 s;
#pragma unroll
        for (int j = 0; j < 4; j++) s[j] = f2bs(f[j]);
        __builtin_memcpy((short*)cb + i * 4, &s, 8);
        return;
    }
    blk -= 4704;
    // LN: one row per wave, f32x4 loads, 64-lane butterfly (no barriers)
    int wave = tid >> 6, lane = tid & 63;
    int row = blk * 4 + wave;
    const float* xr = x + (size_t)row * DIM;
    f32x4 v[3];
    float s = 0.f, ss = 0.f;
#pragma unroll
    for (int i = 0; i < 3; i++) {
        __builtin_memcpy(&v[i], xr + lane * 4 + i * 256, 16);
#pragma unroll
        for (int j = 0; j < 4; j++) { s += v[i][j]; ss += v[i][j] * v[i][j]; }
    }
#pragma unroll
    for (int off = 32; off; off >>= 1) {
        s += __shfl_xor(s, off);
        ss += __shfl_xor(ss, off);
    }
    float mu = s / DIM;
    float rs = rsqrtf(ss / DIM - mu * mu + 1e-5f);
#pragma unroll
    for (int i = 0; i < 3; i++) {
        int c = lane * 4 + i * 256;
        f32x4 g, bt;
        __builtin_memcpy(&g, gamma + c, 16);
        __builtin_memcpy(&bt, beta + c, 16);
        s16x4 o;
#pragma unroll
        for (int j = 0; j < 4; j++) o[j] = f2bs((v[i][j] - mu) * rs * g[j] + bt[j]);
        __builtin_memcpy((short*)xn + (size_t)row * DIM + c, &o, 8);
    }
}

// -------- gemm_q: qbuf(bf16) = xn @ WqT^T (128x128 2-phase, gemm_o clone) --
__global__ __launch_bounds__(256)
void gemm_q(const __hip_bfloat16* __restrict__ A,
            const __hip_bfloat16* __restrict__ BT,
            __hip_bfloat16* __restrict__ C) {
    __shared__ short sA[2][128 * 64];
    __shared__ short sB[2][128 * 64];
    int orig = blockIdx.x;
    int xcd = orig & 7, pos = orig >> 3;
    int wgid = (xcd < 6 ? xcd * 37 : 222 + (xcd - 6) * 36) + pos;
    int mt = wgid / 6, nt = wgid - mt * 6;
    int m0 = mt * 128, n0 = nt * 128;
    int tid = threadIdx.x, lane = tid & 63, wave = tid >> 6;
    int r = lane & 15, q = lane >> 4;
    int wm = (wave & 1) * 64, wn = (wave >> 1) * 64;
    f32x4 acc[4][4] = {};

    auto stage = [&](int buf, int k0) {
#pragma unroll
        for (int i = 0; i < 4; i++) {
            int c = i * 256 + tid;
            int row = c >> 3, cg = c & 7;
            load16_lds(A + (size_t)(m0 + row) * DIM + k0 + cg * 8, &sA[buf][c * 8]);
        }
#pragma unroll
        for (int i = 0; i < 4; i++) {
            int c = i * 256 + tid;
            int row = c >> 3, cg = c & 7;
            load16_lds(BT + (size_t)(n0 + row) * DIM + k0 + cg * 8, &sB[buf][c * 8]);
        }
    };
    auto compute = [&](int buf) {
#pragma unroll
        for (int ks = 0; ks < 2; ks++) {
            short8 af[4], bfv[4];
#pragma unroll
            for (int t = 0; t < 4; t++) {
                __builtin_memcpy(&af[t],  &sA[buf][(wm + t * 16 + r) * 64 + ks * 32 + q * 8], 16);
                __builtin_memcpy(&bfv[t], &sB[buf][(wn + t * 16 + r) * 64 + ks * 32 + q * 8], 16);
            }
            __builtin_amdgcn_s_setprio(1);
#pragma unroll
            for (int mi = 0; mi < 4; mi++)
#pragma unroll
                for (int ni = 0; ni < 4; ni++)
                    acc[mi][ni] = __builtin_amdgcn_mfma_f32_16x16x32_bf16(
                        af[mi], bfv[ni], acc[mi][ni], 0, 0, 0);
            __builtin_amdgcn_s_setprio(0);
        }
    };

    stage(0, 0);
    __syncthreads();
    int cur = 0;
#pragma unroll 2
    for (int t = 0; t < 11; ++t) {
        stage(cur ^ 1, (t + 1) * 64);
        compute(cur);
        __syncthreads();
        cur ^= 1;
    }
    compute(cur);

#pragma unroll
    for (int mi = 0; mi < 4; mi++)
#pragma unroll
        for (int ni = 0; ni < 4; ni++)
#pragma unroll
            for (int rr = 0; rr < 4; rr++) {
                int row = m0 + wm + mi * 16 + q * 4 + rr;
                int col = n0 + wn + ni * 16 + r;
                C[(size_t)row * DIM + col] = __float2bfloat16(acc[mi][ni][rr]);
            }
}

// -------- gemm_o: out(fp32) = qo @ WoT^T + bo (2-phase dbuf, unchanged) ----
__global__ __launch_bounds__(256)
void gemm_o(const __hip_bfloat16* __restrict__ A,
            const __hip_bfloat16* __restrict__ BT,
            const float* __restrict__ bias,
            float* __restrict__ C) {
    __shared__ short sA[2][128 * 64];
    __shared__ short sB[2][128 * 64];
    int orig = blockIdx.x;
    int xcd = orig & 7, pos = orig >> 3;
    int wgid = (xcd < 6 ? xcd * 37 : 222 + (xcd - 6) * 36) + pos;
    int mt = wgid / 6, nt = wgid - mt * 6;
    int m0 = mt * 128, n0 = nt * 128;
    int tid = threadIdx.x, lane = tid & 63, wave = tid >> 6;
    int r = lane & 15, q = lane >> 4;
    int wm = (wave & 1) * 64, wn = (wave >> 1) * 64;
    f32x4 acc[4][4] = {};

    auto stage = [&](int buf, int k0) {
#pragma unroll
        for (int i = 0; i < 4; i++) {
            int c = i * 256 + tid;
            int row = c >> 3, cg = c & 7;
            load16_lds(A + (size_t)(m0 + row) * DIM + k0 + cg * 8, &sA[buf][c * 8]);
        }
#pragma unroll
        for (int i = 0; i < 4; i++) {
            int c = i * 256 + tid;
            int row = c >> 3, cg = c & 7;
            load16_lds(BT + (size_t)(n0 + row) * DIM + k0 + cg * 8, &sB[buf][c * 8]);
        }
    };
    auto compute = [&](int buf) {
#pragma unroll
        for (int ks = 0; ks < 2; ks++) {
            short8 af[4], bfv[4];
#pragma unroll
            for (int t = 0; t < 4; t++) {
                __builtin_memcpy(&af[t],  &sA[buf][(wm + t * 16 + r) * 64 + ks * 32 + q * 8], 16);
                __builtin_memcpy(&bfv[t], &sB[buf][(wn + t * 16 + r) * 64 + ks * 32 + q * 8], 16);
            }
            __builtin_amdgcn_s_setprio(1);
#pragma unroll
            for (int mi = 0; mi < 4; mi++)
#pragma unroll
                for (int ni = 0; ni < 4; ni++)
                    acc[mi][ni] = __builtin_amdgcn_mfma_f32_16x16x32_bf16(
                        af[mi], bfv[ni], acc[mi][ni], 0, 0, 0);
            __builtin_amdgcn_s_setprio(0);
        }
    };

    stage(0, 0);
    __syncthreads();
    int cur = 0;
#pragma unroll 2
    for (int t = 0; t < 11; ++t) {
        stage(cur ^ 1, (t + 1) * 64);
        compute(cur);
        __syncthreads();
        cur ^= 1;
    }
    compute(cur);

    float bv[4];
#pragma unroll
    for (int ni = 0; ni < 4; ni++) bv[ni] = bias[n0 + wn + ni * 16 + r];
#pragma unroll
    for (int mi = 0; mi < 4; mi++)
#pragma unroll
        for (int ni = 0; ni < 4; ni++)
#pragma unroll
            for (int rr = 0; rr < 4; rr++) {
                int row = m0 + wm + mi * 16 + q * 4 + rr;
                int col = n0 + wn + ni * 16 + r;
                C[(size_t)row * DIM + col] = acc[mi][ni][rr] + bv[ni];
            }
}

// -------- attn v4: KV-GEMM fused into attention ----------------------------
// Phase A: K,V = cb[frame] @ WkvT[h-slices] streamed in 12 K-chunks of 64
// (cbS 25088 B + wS 16384 B), acc in regs (2x8 f32x4/wave), committed
// straight into sK/sVT which ALIAS the stream buffers (union 56384 B ->
// 2 blocks/CU kept). Deletes kvbuf 38.6 MB HBM round-trip + the KV GEMM
// kernel. Phase B: v3 QK/softmax/PV unchanged.
__global__ __launch_bounds__(448, 4)
void attn_kernel(__hip_bfloat16* qo,                        // [B*T,768] q in, o out
                 const __hip_bfloat16* __restrict__ cb,     // [B*T,768] ctx bf16
                 const __hip_bfloat16* __restrict__ WkvT) { // [1536][768]
    __shared__ short smem[28192];      // 56,384 B union
    short* cbS = smem;                 // phase A: [196][64] swizzled (25,088 B)
    short* wS  = smem + 12544;         // phase A: [128][64] swizzled (16,384 B)
    short* sK  = smem;                 // phase B: [208][66]          (27,456 B)
    short* sVT = smem + 13728;         // phase B: [64][226]          (28,928 B)
    int blk = blockIdx.x;
    int f = blk % NF, h = (blk / NF) % NH, b = blk / (NF * NH);
    size_t tok0 = (size_t)b * TT + (size_t)f * NP;
    int tid = threadIdx.x, wave = tid >> 6, lane = tid & 63;
    int r = lane & 15, q = lane >> 4;

    // ---- Q fragments for both halves, direct global->reg (latency hides
    // under phase A).
    short8 qf[2][2];
#pragma unroll
    for (int half = 0; half < 2; half++) {
        int qrow = half * 98 + wave * 16 + r;
        if (qrow >= NP) qrow = 0;      // clamped lanes' outputs never stored
        const __hip_bfloat16* src = qo + (tok0 + qrow) * DIM + h * 64;
        __builtin_memcpy(&qf[half][0], src + q * 8, 16);
        __builtin_memcpy(&qf[half][1], src + 32 + q * 8, 16);
    }

    // ---- Phase A: K|V (196 x 128) = cb @ WkvT rows {h*64.., 768+h*64..}
    // wave owns j-frags {2*wave, 2*wave+1} (jf=13 computes garbage, writes
    // guarded). df<4 -> K cols, df>=4 -> V cols.
    f32x4 acc0[8] = {}, acc1[8] = {};
    for (int kc = 0; kc < 12; kc++) {
        if (kc) __syncthreads();               // cbS/wS free for overwrite
        int k0 = kc * 64;
        for (int e = tid; e < 1568; e += 448) {
            int row = e >> 3, cg = e & 7;
            int sw = (cg ^ (row & 7)) << 4;
            load16_lds((const char*)cb + ((size_t)(tok0 + row) * DIM + k0) * 2 + sw,
                       (char*)cbS + e * 16);
        }
        for (int e = tid; e < 1024; e += 448) {
            int row = e >> 3, cg = e & 7;
            int sw = (cg ^ (row & 7)) << 4;
            int wrow = (row < 64) ? (h * 64 + row) : (DIM + h * 64 + row - 64);
            load16_lds((const char*)WkvT + ((size_t)wrow * DIM + k0) * 2 + sw,
                       (char*)wS + e * 16);
        }
        __syncthreads();                       // drains vmcnt -> data ready

        short8 a0[2], a1[2];
#pragma unroll
        for (int ks = 0; ks < 2; ks++) {
            int b0 = (2 * wave * 16 + r) * 128 + ((ks * 64 + q * 16) ^ ((r & 7) << 4));
            int b1 = ((2 * wave + 1) * 16 + r) * 128 + ((ks * 64 + q * 16) ^ ((r & 7) << 4));
            __builtin_memcpy(&a0[ks], (char*)cbS + b0, 16);
            __builtin_memcpy(&a1[ks], (char*)cbS + b1, 16);
        }
        __builtin_amdgcn_s_setprio(1);
#pragma unroll
        for (int df = 0; df < 8; df++)
#pragma unroll
            for (int ks = 0; ks < 2; ks++) {
                short8 bfv;
                int bb = (df * 16 + r) * 128 + ((ks * 64 + q * 16) ^ ((r & 7) << 4));
                __builtin_memcpy(&bfv, (char*)wS + bb, 16);
                acc0[df] = __builtin_amdgcn_mfma_f32_16x16x32_bf16(a0[ks], bfv, acc0[df], 0, 0, 0);
                acc1[df] = __builtin_amdgcn_mfma_f32_16x16x32_bf16(a1[ks], bfv, acc1[df], 0, 0, 0);
            }
        __builtin_amdgcn_s_setprio(0);
    }
    __syncthreads();   // all phase-A LDS reads done -> safe to overwrite union

    // ---- commit acc -> sK (df<4) / sVT (df>=4, transposed scatter)
#pragma unroll
    for (int jj = 0; jj < 2; jj++)
#pragma unroll
        for (int df = 0; df < 8; df++)
#pragma unroll
            for (int i = 0; i < 4; i++) {
                int j = (2 * wave + jj) * 16 + q * 4 + i;
                if (j < NP) {
                    float v = jj ? acc1[df][i] : acc0[df][i];
                    short s = f2bs(v);
                    if (df < 4) sK[j * 66 + df * 16 + r] = s;
                    else        sVT[(df * 16 + r - 64) * 226 + j] = s;
                }
            }
    // zero sK rows 196..207 (QK^T A-operand reads rows < 208; stale union
    // bytes there are masked by softmax but keep them finite anyway)
    for (int e = tid; e < 12 * 66; e += 448) {
        int row = NP + e / 66, c = e % 66;
        sK[row * 66 + c] = 0;
    }
    // zero sVT cols 196..225 (PV reads j<224; stale union data may be NaN)
    for (int e = tid; e < 64 * 30; e += 448) {
        int d = e / 30, j = NP + e % 30;
        sVT[d * 226 + j] = 0;
    }
    __syncthreads();   // sK/sVT ready

    // ---- Phase B: v3 QK^T / softmax / PV, unchanged
#pragma unroll
    for (int half = 0; half < 2; half++) {
        int row0 = half * 98;

        f32x4 sacc[13];
#pragma unroll
        for (int jf = 0; jf < 13; jf++) {
            f32x4 a = {};
            short8 kf;
            __builtin_memcpy(&kf, &sK[(jf * 16 + r) * 66 + q * 8], 16);
            a = __builtin_amdgcn_mfma_f32_16x16x32_bf16(kf, qf[half][0], a, 0, 0, 0);
            __builtin_memcpy(&kf, &sK[(jf * 16 + r) * 66 + 32 + q * 8], 16);
            a = __builtin_amdgcn_mfma_f32_16x16x32_bf16(kf, qf[half][1], a, 0, 0, 0);
            sacc[jf] = a;
        }

        const float scale = 0.125f;
        float mx = -INFINITY;
#pragma unroll
        for (int jf = 0; jf < 13; jf++)
#pragma unroll
            for (int rg = 0; rg < 4; rg++) {
                bool valid = (jf < 12) | (q == 0);
                if (valid) mx = fmaxf(mx, sacc[jf][rg] * scale);
            }
        mx = fmaxf(mx, __shfl_xor(mx, 16));
        mx = fmaxf(mx, __shfl_xor(mx, 32));
        float ps = 0.f;
#pragma unroll
        for (int jf = 0; jf < 13; jf++)
#pragma unroll
            for (int rg = 0; rg < 4; rg++) {
                bool valid = (jf < 12) | (q == 0);
                float p = valid ? __expf(sacc[jf][rg] * scale - mx) : 0.f;
                sacc[jf][rg] = p;
                ps += p;
            }
        ps += __shfl_xor(ps, 16);
        ps += __shfl_xor(ps, 32);
        float inv = 1.f / ps;

        uint pk01[13], pk23[13];
#pragma unroll
        for (int jf = 0; jf < 13; jf++) {
            pk01[jf] = pack2bf(sacc[jf][0] * inv, sacc[jf][1] * inv);
            pk23[jf] = pack2bf(sacc[jf][2] * inv, sacc[jf][3] * inv);
        }
        int sl = (((2 * q) & 3) << 4) | r;
        int sh = (((2 * q + 1) & 3) << 4) | r;
        bool hiq = q >= 2;
        short8 pa[7];
#pragma unroll
        for (int c = 0; c < 7; c++) {
            uint a0 = (uint)__shfl((int)pk01[2 * c], sl, 64);
            uint a1 = (uint)__shfl((int)pk23[2 * c], sl, 64);
            uint a2 = (uint)__shfl((int)pk01[2 * c], sh, 64);
            uint a3 = (uint)__shfl((int)pk23[2 * c], sh, 64);
            uint b0 = 0, b1 = 0, b2 = 0, b3 = 0;
            if (c < 6) {
                b0 = (uint)__shfl((int)pk01[2 * c + 1], sl, 64);
                b1 = (uint)__shfl((int)pk23[2 * c + 1], sl, 64);
                b2 = (uint)__shfl((int)pk01[2 * c + 1], sh, 64);
                b3 = (uint)__shfl((int)pk23[2 * c + 1], sh, 64);
            }
            uint w[4] = { hiq ? b0 : a0, hiq ? b1 : a1, hiq ? b2 : a2, hiq ? b3 : a3 };
            __builtin_memcpy(&pa[c], w, 16);
        }

#pragma unroll
        for (int nt = 0; nt < 4; nt++) {
            f32x4 oacc = {};
#pragma unroll
            for (int kc = 0; kc < 7; kc++) {
                short8 bfv;
                __builtin_memcpy(&bfv, &sVT[(nt * 16 + r) * 226 + kc * 32 + q * 8], 16);
                oacc = __builtin_amdgcn_mfma_f32_16x16x32_bf16(pa[kc], bfv, oacc, 0, 0, 0);
            }
#pragma unroll
            for (int rg = 0; rg < 4; rg++) {
                int local = wave * 16 + q * 4 + rg;
                if (local < 98)
                    qo[(tok0 + row0 + local) * DIM + h * 64 + nt * 16 + r] =
                        __float2bfloat16(oacc[rg]);
            }
        }
    }
}

extern "C" void kernel_launch(void* const* d_in, const int* in_sizes, int n_in,
                              void* d_out, int out_size, void* d_ws, size_t ws_size,
                              hipStream_t stream) {
    const float* x     = (const float*)d_in[0];
    const float* ctx   = (const float*)d_in[1];
    const float* Wq    = (const float*)d_in[2];
    const float* Wkv   = (const float*)d_in[3];
    const float* Wo    = (const float*)d_in[4];
    const float* bo    = (const float*)d_in[5];
    const float* gamma = (const float*)d_in[6];
    const float* beta  = (const float*)d_in[7];
    // d_in[8] = mask: block-diagonal by frame, recomputed structurally.

    char* ws = (char*)d_ws;
    __hip_bfloat16* cbuf  = (__hip_bfloat16*)(ws + 0);           //  9,633,792
    __hip_bfloat16* qbuf  = (__hip_bfloat16*)(ws + 9633792);     //  9,633,792
    __hip_bfloat16* WqT   = (__hip_bfloat16*)(ws + 19267584);    //  1,179,648
    __hip_bfloat16* WkvT  = (__hip_bfloat16*)(ws + 20447232);    //  2,359,296
    __hip_bfloat16* WoT   = (__hip_bfloat16*)(ws + 22806528);    //  1,179,648
    __hip_bfloat16* xnbuf = (__hip_bfloat16*)d_out;              //  dead until gemm_o
    float*          out   = (float*)d_out;

    prep_all<<<8576, 256, 0, stream>>>(Wq, Wkv, Wo, WqT, WkvT, WoT,
                                       ctx, cbuf, x, gamma, beta, xnbuf);
    gemm_q<<<294, 256, 0, stream>>>(xnbuf, WqT, qbuf);
    attn_kernel<<<NB * NH * NF, 448, 0, stream>>>(qbuf, cbuf, WkvT);
    gemm_o<<<294, 256, 0, stream>>>(qbuf, WoT, bo, out);
}